// Round 12
// baseline (252.562 us; speedup 1.0000x reference)
//
#include <hip/hip_runtime.h>
#include <stdint.h>

#define NT 256
#define CHUNK 4096
#define BSHIFT 8

typedef __attribute__((ext_vector_type(8))) short bf16x8;
typedef __attribute__((ext_vector_type(4))) float f32x4;

__device__ __forceinline__ float lrelu(float x) { return x > 0.f ? x : 0.2f * x; }

__device__ __forceinline__ float b2f(unsigned short u) {
  union { unsigned int i; float f; } v; v.i = ((unsigned int)u) << 16; return v.f;
}
__device__ __forceinline__ unsigned short f2b(float f) {
  unsigned int u = __float_as_uint(f);
  return (unsigned short)((u + 0x7fffu + ((u >> 16) & 1u)) >> 16);   // RNE
}

// ---- edge dtype detection (int32 vs int64) ----
__global__ void detect_kernel(const int* __restrict__ ei, int* __restrict__ flag, int twoE) {
  __shared__ int any;
  if (threadIdx.x == 0) any = 0;
  __syncthreads();
  int n = twoE < 4096 ? twoE : 4096;
  for (int i = threadIdx.x * 2 + 1; i < n; i += 2 * NT)
    if (ei[i] != 0) any = 1;   // benign race, same value
  __syncthreads();
  if (threadIdx.x == 0) *flag = any;   // 1 -> int32 data, 0 -> int64
}

// ---- fused: convert edges + per-block bucket histogram ----
__global__ void cvtbin_kernel(const void* __restrict__ ei, const int* __restrict__ flag,
                              int* __restrict__ edges, int* __restrict__ blkcnt,
                              int E, int nblk, int nbk) {
  __shared__ int cnt[256];
  int b = blockIdx.x;
  for (int i = threadIdx.x; i < nbk; i += NT) cnt[i] = 0;
  __syncthreads();
  int beg = b * CHUNK;
  int end = beg + CHUNK < E ? beg + CHUNK : E;
  bool is32 = (*flag != 0);
  for (int i = beg + threadIdx.x; i < end; i += NT) {
    int s, d;
    if (is32) { s = ((const int*)ei)[i]; d = ((const int*)ei)[E + i]; }
    else      { s = (int)((const long long*)ei)[i]; d = (int)((const long long*)ei)[E + i]; }
    edges[i] = s;
    edges[E + i] = d;
    atomicAdd(&cnt[d >> BSHIFT], 1);
  }
  __syncthreads();
  for (int i = threadIdx.x; i < nbk; i += NT) blkcnt[i * nblk + b] = cnt[i];
}

__global__ void zero2_kernel(int* __restrict__ a, int* __restrict__ b, int n) {
  int i = blockIdx.x * NT + threadIdx.x;
  if (i < n) { a[i] = 0; b[i] = 0; }
}

// ---- generic scan trio ----
__global__ void scan1_kernel(const int* __restrict__ in, int* __restrict__ bsum, int n) {
  __shared__ int sm[NT];
  int idx = blockIdx.x * NT + threadIdx.x;
  sm[threadIdx.x] = (idx < n) ? in[idx] : 0;
  __syncthreads();
  for (int s = NT / 2; s > 0; s >>= 1) {
    if (threadIdx.x < s) sm[threadIdx.x] += sm[threadIdx.x + s];
    __syncthreads();
  }
  if (threadIdx.x == 0) bsum[blockIdx.x] = sm[0];
}

__global__ void scan2_kernel(const int* __restrict__ bsum, int* __restrict__ boff, int SB) {
  __shared__ int sm[NT];
  int t = threadIdx.x;
  int v = (t < SB) ? bsum[t] : 0;
  sm[t] = v;
  __syncthreads();
  for (int s = 1; s < NT; s <<= 1) {
    int add = (t >= s) ? sm[t - s] : 0;
    __syncthreads();
    sm[t] += add;
    __syncthreads();
  }
  if (t < SB) boff[t] = sm[t] - v;   // exclusive
}

__global__ void scan3_kernel(const int* __restrict__ in, const int* __restrict__ boff,
                             int* __restrict__ out, int n) {
  __shared__ int sm[NT];
  int idx = blockIdx.x * NT + threadIdx.x;
  int v = (idx < n) ? in[idx] : 0;
  sm[threadIdx.x] = v;
  __syncthreads();
  for (int s = 1; s < NT; s <<= 1) {
    int add = (threadIdx.x >= s) ? sm[threadIdx.x - s] : 0;
    __syncthreads();
    sm[threadIdx.x] += add;
    __syncthreads();
  }
  if (idx <= n) out[idx] = boff[blockIdx.x] + sm[threadIdx.x] - v;  // exclusive
}

// ---- bucket-contiguous write of packed (dst,src) ----
__global__ void binwrite_kernel(const int* __restrict__ src, const int* __restrict__ dst,
                                const int* __restrict__ base, long long* __restrict__ binned,
                                int E, int nblk, int nbk) {
  __shared__ int cnt[256];
  int b = blockIdx.x;
  for (int i = threadIdx.x; i < nbk; i += NT) cnt[i] = base[i * nblk + b];
  __syncthreads();
  int beg = b * CHUNK;
  int end = beg + CHUNK < E ? beg + CHUNK : E;
  for (int i = beg + threadIdx.x; i < end; i += NT) {
    int d = dst[i];
    int pos = atomicAdd(&cnt[d >> BSHIFT], 1);
    binned[pos] = ((long long)d << 32) | (unsigned int)src[i];
  }
}

// ---- degree histogram from binned (bucket-local atomics) ----
__global__ void deghist_kernel(const long long* __restrict__ binned, int* __restrict__ deg, int E) {
  int e = blockIdx.x * NT + threadIdx.x;
  if (e < E) atomicAdd(&deg[(int)(binned[e] >> 32)], 1);
}

// ---- locality-friendly scatter to CSR ----
__global__ void scatter2_kernel(const long long* __restrict__ binned, const int* __restrict__ rowptr,
                                int* __restrict__ cursor, int* __restrict__ csr_src, int E) {
  int e = blockIdx.x * NT + threadIdx.x;
  if (e >= E) return;
  long long v = binned[e];
  int d = (int)(v >> 32);
  int s = (int)(v & 0xffffffffLL);
  int pos = rowptr[d] + atomicAdd(&cursor[d], 1);
  csr_src[pos] = s;
}

// ---- pack W1 into MFMA B-fragment lane order (bf16) ----
__global__ void foldB1_kernel(const float* __restrict__ W1, unsigned short* __restrict__ W1pack) {
  int idx = blockIdx.x * NT + threadIdx.x;   // over 128*64
  if (idx >= 128 * 64) return;
  int j = idx & 7;
  int lane = (idx >> 3) & 63;
  int ctchunk = idx >> 9;
  int ct = ctchunk & 3;
  int chunk = ctchunk >> 2;
  int k = chunk * 32 + ((lane >> 4) << 3) + j;
  int col = ct * 16 + (lane & 15);
  W1pack[idx] = f2b(W1[k * 64 + col]);
}

// ---- layer 1 MFMA GEMM + fused attention dots ----
__global__ void __launch_bounds__(NT)
gemm1_mfma_kernel(const float* __restrict__ x, const unsigned short* __restrict__ W1pack,
                  const float* __restrict__ attl, const float* __restrict__ attr,
                  unsigned short* __restrict__ xl1b, float* __restrict__ a1, int N) {
  int w = threadIdx.x >> 6;
  int lane = threadIdx.x & 63;
  int colb = lane & 15;
  int rgrp = lane >> 4;            // 0..3
  int row0w = blockIdx.x * 64 + w * 16;
  int arow = row0w + colb;
  if (arow >= N) arow = N - 1;     // clamp; stores guarded
  const float* ap = x + (size_t)arow * 128 + (rgrp << 3);

  f32x4 acc[4];
#pragma unroll
  for (int ct = 0; ct < 4; ++ct) { acc[ct][0] = 0.f; acc[ct][1] = 0.f; acc[ct][2] = 0.f; acc[ct][3] = 0.f; }

#pragma unroll
  for (int chunk = 0; chunk < 4; ++chunk) {
    float4 v0 = *(const float4*)(ap + chunk * 32);
    float4 v1 = *(const float4*)(ap + chunk * 32 + 4);
    bf16x8 a;
    a[0] = (short)f2b(v0.x); a[1] = (short)f2b(v0.y);
    a[2] = (short)f2b(v0.z); a[3] = (short)f2b(v0.w);
    a[4] = (short)f2b(v1.x); a[5] = (short)f2b(v1.y);
    a[6] = (short)f2b(v1.z); a[7] = (short)f2b(v1.w);
    const unsigned short* bp = W1pack + ((size_t)chunk * 4 * 64 + lane) * 8;
#pragma unroll
    for (int ct = 0; ct < 4; ++ct) {
      bf16x8 b = *(const bf16x8*)(bp + (size_t)ct * 64 * 8);
      acc[ct] = __builtin_amdgcn_mfma_f32_16x16x32_bf16(a, b, acc[ct], 0, 0, 0);
    }
  }

#pragma unroll
  for (int ct = 0; ct < 4; ++ct) {
    float attlc = attl[ct * 16 + colb];
    float attrc = attr[ct * 16 + colb];
    int h = ct * 2 + (colb >> 3);
#pragma unroll
    for (int r = 0; r < 4; ++r) {
      int n = row0w + rgrp * 4 + r;
      float v = acc[ct][r];
      if (n < N) xl1b[(size_t)n * 64 + ct * 16 + colb] = f2b(v);
      float pl = v * attlc;
      float pr = v * attrc;
      pl += __shfl_xor(pl, 1, 64); pr += __shfl_xor(pr, 1, 64);
      pl += __shfl_xor(pl, 2, 64); pr += __shfl_xor(pr, 2, 64);
      pl += __shfl_xor(pl, 4, 64); pr += __shfl_xor(pr, 4, 64);
      if ((lane & 7) == 0 && n < N) {
        a1[n * 16 + h] = pl;
        a1[n * 16 + 8 + h] = pr;
      }
    }
  }
}

// ---- fold W2 with att vectors ----
__global__ void foldw_kernel(const float* __restrict__ W2, const float* __restrict__ attl2,
                             const float* __restrict__ attr2, float* __restrict__ wl,
                             float* __restrict__ wr) {
  int t = threadIdx.x;           // 0..511
  int k = t >> 3, h = t & 7;
  float sl = 0.f, sr = 0.f;
  for (int f = 0; f < 64; ++f) {
    float w = W2[k * 512 + h * 64 + f];
    sl += w * attl2[h * 64 + f];
    sr += w * attr2[h * 64 + f];
  }
  wl[k * 8 + h] = sl;
  wr[k * 8 + h] = sr;
}

// ---- pack B fragments for MFMA epilogue (layer-2 W2, head-mean folded) ----
__global__ void foldB_kernel(const float* __restrict__ W2, unsigned short* __restrict__ Bpack) {
  int idx = blockIdx.x * NT + threadIdx.x;   // over 512*64
  if (idx >= 512 * 64) return;
  int j = idx & 7;
  int lane = (idx >> 3) & 63;
  int ctchunk = idx >> 9;
  int ct = ctchunk & 3;
  int chunk = ctchunk >> 2;
  int hk = chunk * 32 + ((lane >> 4) << 3) + j;
  int h = hk >> 6, kk = hk & 63;
  int f = ct * 16 + (lane & 15);
  Bpack[idx] = f2b(W2[kk * 512 + h * 64 + f] * 0.125f);
}

// ---- layer1: single-pass softmax+aggregation ----
__global__ void __launch_bounds__(NT)
node_aggr1_kernel(const int* __restrict__ rowptr, const int* __restrict__ csr_src,
                  const float* __restrict__ a1, const unsigned short* __restrict__ xl1b,
                  const float* __restrict__ b1, unsigned short* __restrict__ hrb, int N) {
  __shared__ float ps[4][64][8];
  __shared__ int ss[4][64];
  int w = threadIdx.x >> 6;
  int n = blockIdx.x * 4 + w;
  if (n >= N) return;
  int lane = threadIdx.x & 63;
  int hstage = lane & 7;
  int j8 = lane >> 3;
  int hown = lane >> 3;
  int base = rowptr[n];
  int deg = rowptr[n + 1] - base;

  float arh = a1[n * 16 + 8 + hstage];
  const unsigned short* xp = xl1b + lane;
  float acc = 0.f, dn = 0.f;

  for (int j0 = 0; j0 < deg; j0 += 64) {
    int cnt = deg - j0; if (cnt > 64) cnt = 64;
    if (lane < cnt) ss[w][lane] = csr_src[base + j0 + lane];
    asm volatile("s_waitcnt lgkmcnt(0)" ::: "memory");
    for (int jj = 0; jj < cnt; jj += 8) {
      int j = jj + j8;
      if (j < cnt) {
        int s = ss[w][j];
        float p = __expf(lrelu(a1[(unsigned)s * 16 + hstage] + arh));
        ps[w][j][hstage] = p;
      }
    }
    asm volatile("s_waitcnt lgkmcnt(0)" ::: "memory");
    int j = 0;
    for (; j + 4 <= cnt; j += 4) {
      int s0 = ss[w][j+0], s1 = ss[w][j+1], s2 = ss[w][j+2], s3 = ss[w][j+3];
      float p0 = ps[w][j+0][hown], p1 = ps[w][j+1][hown];
      float p2 = ps[w][j+2][hown], p3 = ps[w][j+3][hown];
      float v0 = b2f(xp[(unsigned)s0 * 64]), v1 = b2f(xp[(unsigned)s1 * 64]);
      float v2 = b2f(xp[(unsigned)s2 * 64]), v3 = b2f(xp[(unsigned)s3 * 64]);
      dn += (p0 + p1) + (p2 + p3);
      acc += p0 * v0 + p1 * v1 + p2 * v2 + p3 * v3;
    }
    for (; j < cnt; ++j) {
      int s = ss[w][j];
      float p = ps[w][j][hown];
      dn += p;
      acc += p * b2f(xp[(unsigned)s * 64]);
    }
  }
  acc = acc / (dn + 1e-16f);
  float hv = fmaxf(acc + b1[lane], 0.f);   // relu(out1 + b1)
  hrb[(size_t)n * 64 + lane] = f2b(hv);
}

// ---- layer-2 attention dots as a streaming kernel ----
#define A2N 256
__global__ void __launch_bounds__(NT)
a2dots_kernel(const unsigned short* __restrict__ hrb, const float* __restrict__ wl,
              const float* __restrict__ wr, float* __restrict__ a2, int N) {
  __shared__ unsigned short hs[A2N][65];
  __shared__ float wls[64 * 8], wrs[64 * 8];
  int tid = threadIdx.x;
  int n0 = blockIdx.x * A2N;
  for (int i = tid; i < 512; i += NT) { wls[i] = wl[i]; wrs[i] = wr[i]; }
  for (int i = tid; i < A2N * 8; i += NT) {
    int r = i >> 3, seg = i & 7;
    int n = n0 + r;
    uint4 v = make_uint4(0, 0, 0, 0);
    if (n < N) v = *(const uint4*)&hrb[(size_t)n * 64 + seg * 8];
    int c = seg * 8;
    hs[r][c + 0] = (unsigned short)(v.x);
    hs[r][c + 1] = (unsigned short)(v.x >> 16);
    hs[r][c + 2] = (unsigned short)(v.y);
    hs[r][c + 3] = (unsigned short)(v.y >> 16);
    hs[r][c + 4] = (unsigned short)(v.z);
    hs[r][c + 5] = (unsigned short)(v.z >> 16);
    hs[r][c + 6] = (unsigned short)(v.w);
    hs[r][c + 7] = (unsigned short)(v.w >> 16);
  }
  __syncthreads();
  float tl[8], tr[8];
#pragma unroll
  for (int h = 0; h < 8; ++h) { tl[h] = 0.f; tr[h] = 0.f; }
#pragma unroll 4
  for (int k = 0; k < 64; ++k) {
    float hv = b2f(hs[tid][k]);
    float4 l0 = *(const float4*)&wls[k * 8];
    float4 l1 = *(const float4*)&wls[k * 8 + 4];
    float4 r0 = *(const float4*)&wrs[k * 8];
    float4 r1 = *(const float4*)&wrs[k * 8 + 4];
    tl[0] += hv * l0.x; tl[1] += hv * l0.y; tl[2] += hv * l0.z; tl[3] += hv * l0.w;
    tl[4] += hv * l1.x; tl[5] += hv * l1.y; tl[6] += hv * l1.z; tl[7] += hv * l1.w;
    tr[0] += hv * r0.x; tr[1] += hv * r0.y; tr[2] += hv * r0.z; tr[3] += hv * r0.w;
    tr[4] += hv * r1.x; tr[5] += hv * r1.y; tr[6] += hv * r1.z; tr[7] += hv * r1.w;
  }
  int n = n0 + tid;
  if (n < N) {
    *(float4*)&a2[n * 16 + 0]  = make_float4(tl[0], tl[1], tl[2], tl[3]);
    *(float4*)&a2[n * 16 + 4]  = make_float4(tl[4], tl[5], tl[6], tl[7]);
    *(float4*)&a2[n * 16 + 8]  = make_float4(tr[0], tr[1], tr[2], tr[3]);
    *(float4*)&a2[n * 16 + 12] = make_float4(tr[4], tr[5], tr[6], tr[7]);
  }
}

// ---- layer2 FUSED: softmax+aggregation -> LDS g tile -> MFMA W2 epilogue -> out ----
// 16 nodes/block: wave w aggregates nodes w*4..w*4+3 sequentially, then the block
// contracts gs[16][512] with Bpack (wave w owns col-block ct=w).
__global__ void __launch_bounds__(NT)
node_aggr2_fused_kernel(const int* __restrict__ rowptr, const int* __restrict__ csr_src,
                        const float* __restrict__ a2, const unsigned short* __restrict__ hrb,
                        const unsigned short* __restrict__ Bpack, const float* __restrict__ b2,
                        float* __restrict__ out, int N) {
  __shared__ float ps[4][64][8];
  __shared__ int ss[4][64];
  __shared__ unsigned short gs[16][520];   // pad 520: row stride 1040B -> 2-way banks (free)
  int w = threadIdx.x >> 6;
  int lane = threadIdx.x & 63;
  int hstage = lane & 7;
  int j8 = lane >> 3;

  for (int nr = 0; nr < 4; ++nr) {
    int row = w * 4 + nr;
    int n = blockIdx.x * 16 + row;
    if (n < N) {
      int base = rowptr[n];
      int deg = rowptr[n + 1] - base;
      float arh = a2[n * 16 + 8 + hstage];
      const unsigned short* hp = hrb + lane;
      float acc[8] = {0.f, 0.f, 0.f, 0.f, 0.f, 0.f, 0.f, 0.f};
      float dn_own = 0.f;

      for (int j0 = 0; j0 < deg; j0 += 64) {
        int cnt = deg - j0; if (cnt > 64) cnt = 64;
        if (lane < cnt) ss[w][lane] = csr_src[base + j0 + lane];
        asm volatile("s_waitcnt lgkmcnt(0)" ::: "memory");
        for (int jj = 0; jj < cnt; jj += 8) {
          int j = jj + j8;
          if (j < cnt) {
            int s = ss[w][j];
            float p = __expf(lrelu(a2[(unsigned)s * 16 + hstage] + arh));
            ps[w][j][hstage] = p;
          }
        }
        asm volatile("s_waitcnt lgkmcnt(0)" ::: "memory");
        for (int j = 0; j < cnt; ++j) {
          int s = ss[w][j];
          float hv = b2f(hp[(unsigned)s * 64]);
          float4 pa = *(const float4*)&ps[w][j][0];
          float4 pb = *(const float4*)&ps[w][j][4];
          dn_own += ps[w][j][hstage];
          acc[0] += pa.x * hv; acc[1] += pa.y * hv; acc[2] += pa.z * hv; acc[3] += pa.w * hv;
          acc[4] += pb.x * hv; acc[5] += pb.y * hv; acc[6] += pb.z * hv; acc[7] += pb.w * hv;
        }
      }
#pragma unroll
      for (int h = 0; h < 8; ++h) {
        float dnh = __shfl(dn_own, h, 64);
        float v = acc[h] * (1.f / (dnh + 1e-16f));
        gs[row][h * 64 + lane] = f2b(v);
      }
    } else {
#pragma unroll
      for (int h = 0; h < 8; ++h) gs[row][h * 64 + lane] = 0;
    }
  }
  __syncthreads();

  // MFMA tail: wave w computes cols [w*16, w*16+16)
  f32x4 acc4;
  {
    float bb = b2[w * 16 + (lane & 15)];
    acc4[0] = bb; acc4[1] = bb; acc4[2] = bb; acc4[3] = bb;
  }
  const unsigned short* ap = &gs[lane & 15][(lane >> 4) << 3];
#pragma unroll
  for (int chunk = 0; chunk < 16; ++chunk) {
    bf16x8 a = *(const bf16x8*)(ap + chunk * 32);
    bf16x8 b = *(const bf16x8*)(Bpack + ((size_t)(chunk * 4 + w) * 64 + lane) * 8);
    acc4 = __builtin_amdgcn_mfma_f32_16x16x32_bf16(a, b, acc4, 0, 0, 0);
  }
  int col = w * 16 + (lane & 15);
  int orow0 = (lane >> 4) << 2;
#pragma unroll
  for (int r = 0; r < 4; ++r) {
    int n = blockIdx.x * 16 + orow0 + r;
    if (n < N) out[(size_t)n * 64 + col] = acc4[r];
  }
}

extern "C" void kernel_launch(void* const* d_in, const int* in_sizes, int n_in,
                              void* d_out, int out_size, void* d_ws, size_t ws_size,
                              hipStream_t stream) {
  const float* x     = (const float*)d_in[0];
  const void*  ei    = d_in[1];
  const float* W1    = (const float*)d_in[2];
  const float* attl1 = (const float*)d_in[3];
  const float* attr1 = (const float*)d_in[4];
  const float* b1    = (const float*)d_in[5];
  const float* W2    = (const float*)d_in[6];
  const float* attl2 = (const float*)d_in[7];
  const float* attr2 = (const float*)d_in[8];
  const float* b2    = (const float*)d_in[9];
  float* out = (float*)d_out;

  int N = in_sizes[0] / 128;
  int E = in_sizes[1] / 2;

  int nblk = (E + CHUNK - 1) / CHUNK;
  int nbk  = (N + (1 << BSHIFT) - 1) >> BSHIFT;
  int L    = nbk * nblk;

  char* ws = (char*)d_ws;
  size_t off = 0;
  auto alloc = [&](size_t bytes) {
    char* p = ws + off;
    off += (bytes + 255) & ~size_t(255);
    return p;
  };
  int*            edges   = (int*)alloc((size_t)2 * E * 4);
  int*            flag    = (int*)alloc(256);
  int*            deg     = (int*)alloc((size_t)N * 4);
  int*            cursor  = (int*)alloc((size_t)N * 4);
  int*            rowptr  = (int*)alloc((size_t)(N + 1) * 4);
  int*            bsum    = (int*)alloc(1024);
  int*            boff    = (int*)alloc(1024);
  int*            blkcnt  = (int*)alloc((size_t)L * 4);
  int*            basebuf = (int*)alloc((size_t)(L + 1) * 4);
  int*            bsum2   = (int*)alloc(1024);
  int*            boff2   = (int*)alloc(1024);
  long long*      binned  = (long long*)alloc((size_t)E * 8);
  int*            csr_src = (int*)alloc((size_t)E * 4);
  unsigned short* xl1b    = (unsigned short*)alloc((size_t)N * 64 * 2);
  float*          a1      = (float*)alloc((size_t)N * 16 * 4);
  unsigned short* hrb     = (unsigned short*)alloc((size_t)N * 64 * 2);
  float*          a2      = (float*)alloc((size_t)N * 16 * 4);
  float*          wl      = (float*)alloc(64 * 8 * 4);
  float*          wr      = (float*)alloc(64 * 8 * 4);
  unsigned short* Bpack   = (unsigned short*)alloc(512 * 64 * 2);
  unsigned short* W1pack  = (unsigned short*)alloc(128 * 64 * 2);
  (void)ws_size;

  const int* srcp = edges;
  const int* dstp = edges + E;
  int SB  = (N + 1 + NT - 1) / NT;    // <= 256
  int SBL = (L + 1 + NT - 1) / NT;    // <= 256

  detect_kernel<<<1, NT, 0, stream>>>((const int*)ei, flag, 2 * E);
  zero2_kernel<<<(N + NT - 1) / NT, NT, 0, stream>>>(deg, cursor, N);

  // phase A: fused convert + bucket histogram, then scan + bucket-contiguous write
  cvtbin_kernel<<<nblk, NT, 0, stream>>>(ei, flag, edges, blkcnt, E, nblk, nbk);
  scan1_kernel<<<SBL, NT, 0, stream>>>(blkcnt, bsum2, L);
  scan2_kernel<<<1, NT, 0, stream>>>(bsum2, boff2, SBL);
  scan3_kernel<<<SBL, NT, 0, stream>>>(blkcnt, boff2, basebuf, L);
  binwrite_kernel<<<nblk, NT, 0, stream>>>(srcp, dstp, basebuf, binned, E, nblk, nbk);

  // degree histogram (bucket-local) + rowptr
  deghist_kernel<<<(E + NT - 1) / NT, NT, 0, stream>>>(binned, deg, E);
  scan1_kernel<<<SB, NT, 0, stream>>>(deg, bsum, N);
  scan2_kernel<<<1, NT, 0, stream>>>(bsum, boff, SB);
  scan3_kernel<<<SB, NT, 0, stream>>>(deg, boff, rowptr, N);

  // phase B: locality-friendly CSR scatter
  scatter2_kernel<<<(E + NT - 1) / NT, NT, 0, stream>>>(binned, rowptr, cursor, csr_src, E);

  // dense precomputation
  foldB1_kernel<<<(128 * 64 + NT - 1) / NT, NT, 0, stream>>>(W1, W1pack);
  gemm1_mfma_kernel<<<(N + 63) / 64, NT, 0, stream>>>(x, W1pack, attl1, attr1, xl1b, a1, N);
  foldw_kernel<<<1, 512, 0, stream>>>(W2, attl2, attr2, wl, wr);
  foldB_kernel<<<(512 * 64 + NT - 1) / NT, NT, 0, stream>>>(W2, Bpack);

  // layer 1 aggregation (+ fused relu/bias)
  node_aggr1_kernel<<<(N + 3) / 4, NT, 0, stream>>>(rowptr, csr_src, a1, xl1b, b1, hrb, N);

  // layer-2 attention dots (streaming)
  a2dots_kernel<<<(N + A2N - 1) / A2N, NT, 0, stream>>>(hrb, wl, wr, a2, N);

  // layer 2 aggregation + fused MFMA W2 epilogue -> out
  node_aggr2_fused_kernel<<<(N + 15) / 16, NT, 0, stream>>>(rowptr, csr_src, a2, hrb, Bpack, b2, out, N);
}

// Round 13
// 212.386 us; speedup vs baseline: 1.1892x; 1.1892x over previous
//
#include <hip/hip_runtime.h>
#include <stdint.h>

#define NT 256
#define CHUNK 4096
#define BSHIFT 8

typedef __attribute__((ext_vector_type(8))) short bf16x8;
typedef __attribute__((ext_vector_type(4))) float f32x4;

__device__ __forceinline__ float lrelu(float x) { return x > 0.f ? x : 0.2f * x; }

__device__ __forceinline__ float b2f(unsigned short u) {
  union { unsigned int i; float f; } v; v.i = ((unsigned int)u) << 16; return v.f;
}
__device__ __forceinline__ unsigned short f2b(float f) {
  unsigned int u = __float_as_uint(f);
  return (unsigned short)((u + 0x7fffu + ((u >> 16) & 1u)) >> 16);   // RNE
}

// ---- edge dtype detection (int32 vs int64) ----
__global__ void detect_kernel(const int* __restrict__ ei, int* __restrict__ flag, int twoE) {
  __shared__ int any;
  if (threadIdx.x == 0) any = 0;
  __syncthreads();
  int n = twoE < 4096 ? twoE : 4096;
  for (int i = threadIdx.x * 2 + 1; i < n; i += 2 * NT)
    if (ei[i] != 0) any = 1;   // benign race, same value
  __syncthreads();
  if (threadIdx.x == 0) *flag = any;   // 1 -> int32 data, 0 -> int64
}

// ---- fused: convert edges + per-block bucket histogram + zero deg/cursor ----
__global__ void cvtbin_kernel(const void* __restrict__ ei, const int* __restrict__ flag,
                              int* __restrict__ edges, int* __restrict__ blkcnt,
                              int* __restrict__ deg, int* __restrict__ cursor,
                              int E, int N, int nblk, int nbk) {
  __shared__ int cnt[256];
  int b = blockIdx.x;
  // fused zeroing of deg/cursor (grid covers max(nblk, ceil(N/NT)))
  int zi = b * NT + threadIdx.x;
  if (zi < N) { deg[zi] = 0; cursor[zi] = 0; }
  if (b >= nblk) return;
  for (int i = threadIdx.x; i < nbk; i += NT) cnt[i] = 0;
  __syncthreads();
  int beg = b * CHUNK;
  int end = beg + CHUNK < E ? beg + CHUNK : E;
  bool is32 = (*flag != 0);
  for (int i = beg + threadIdx.x; i < end; i += NT) {
    int s, d;
    if (is32) { s = ((const int*)ei)[i]; d = ((const int*)ei)[E + i]; }
    else      { s = (int)((const long long*)ei)[i]; d = (int)((const long long*)ei)[E + i]; }
    edges[i] = s;
    edges[E + i] = d;
    atomicAdd(&cnt[d >> BSHIFT], 1);
  }
  __syncthreads();
  for (int i = threadIdx.x; i < nbk; i += NT) blkcnt[i * nblk + b] = cnt[i];
}

// ---- generic scan trio ----
__global__ void scan1_kernel(const int* __restrict__ in, int* __restrict__ bsum, int n) {
  __shared__ int sm[NT];
  int idx = blockIdx.x * NT + threadIdx.x;
  sm[threadIdx.x] = (idx < n) ? in[idx] : 0;
  __syncthreads();
  for (int s = NT / 2; s > 0; s >>= 1) {
    if (threadIdx.x < s) sm[threadIdx.x] += sm[threadIdx.x + s];
    __syncthreads();
  }
  if (threadIdx.x == 0) bsum[blockIdx.x] = sm[0];
}

__global__ void scan2_kernel(const int* __restrict__ bsum, int* __restrict__ boff, int SB) {
  __shared__ int sm[NT];
  int t = threadIdx.x;
  int v = (t < SB) ? bsum[t] : 0;
  sm[t] = v;
  __syncthreads();
  for (int s = 1; s < NT; s <<= 1) {
    int add = (t >= s) ? sm[t - s] : 0;
    __syncthreads();
    sm[t] += add;
    __syncthreads();
  }
  if (t < SB) boff[t] = sm[t] - v;   // exclusive
}

__global__ void scan3_kernel(const int* __restrict__ in, const int* __restrict__ boff,
                             int* __restrict__ out, int n) {
  __shared__ int sm[NT];
  int idx = blockIdx.x * NT + threadIdx.x;
  int v = (idx < n) ? in[idx] : 0;
  sm[threadIdx.x] = v;
  __syncthreads();
  for (int s = 1; s < NT; s <<= 1) {
    int add = (threadIdx.x >= s) ? sm[threadIdx.x - s] : 0;
    __syncthreads();
    sm[threadIdx.x] += add;
    __syncthreads();
  }
  if (idx <= n) out[idx] = boff[blockIdx.x] + sm[threadIdx.x] - v;  // exclusive
}

// ---- bucket-contiguous write of packed (dst,src) ----
__global__ void binwrite_kernel(const int* __restrict__ src, const int* __restrict__ dst,
                                const int* __restrict__ base, long long* __restrict__ binned,
                                int E, int nblk, int nbk) {
  __shared__ int cnt[256];
  int b = blockIdx.x;
  for (int i = threadIdx.x; i < nbk; i += NT) cnt[i] = base[i * nblk + b];
  __syncthreads();
  int beg = b * CHUNK;
  int end = beg + CHUNK < E ? beg + CHUNK : E;
  for (int i = beg + threadIdx.x; i < end; i += NT) {
    int d = dst[i];
    int pos = atomicAdd(&cnt[d >> BSHIFT], 1);
    binned[pos] = ((long long)d << 32) | (unsigned int)src[i];
  }
}

// ---- degree histogram from binned (bucket-local atomics) ----
__global__ void deghist_kernel(const long long* __restrict__ binned, int* __restrict__ deg, int E) {
  int e = blockIdx.x * NT + threadIdx.x;
  if (e < E) atomicAdd(&deg[(int)(binned[e] >> 32)], 1);
}

// ---- locality-friendly scatter to CSR ----
__global__ void scatter2_kernel(const long long* __restrict__ binned, const int* __restrict__ rowptr,
                                int* __restrict__ cursor, int* __restrict__ csr_src, int E) {
  int e = blockIdx.x * NT + threadIdx.x;
  if (e >= E) return;
  long long v = binned[e];
  int d = (int)(v >> 32);
  int s = (int)(v & 0xffffffffLL);
  int pos = rowptr[d] + atomicAdd(&cursor[d], 1);
  csr_src[pos] = s;
}

// ---- fused weight packing: foldB (W2->Bpack) + foldB1 (W1->W1pack) + foldw ----
__global__ void foldall_kernel(const float* __restrict__ W1, const float* __restrict__ W2,
                               const float* __restrict__ attl2, const float* __restrict__ attr2,
                               unsigned short* __restrict__ W1pack, unsigned short* __restrict__ Bpack,
                               float* __restrict__ wl, float* __restrict__ wr) {
  int b = blockIdx.x;
  if (b < 128) {
    // foldB: idx over 512*64
    int idx = b * NT + threadIdx.x;
    int j = idx & 7;
    int lane = (idx >> 3) & 63;
    int ctchunk = idx >> 9;
    int ct = ctchunk & 3;
    int chunk = ctchunk >> 2;
    int hk = chunk * 32 + ((lane >> 4) << 3) + j;
    int h = hk >> 6, kk = hk & 63;
    int f = ct * 16 + (lane & 15);
    Bpack[idx] = f2b(W2[kk * 512 + h * 64 + f] * 0.125f);
  } else if (b < 160) {
    // foldB1: idx over 128*64
    int idx = (b - 128) * NT + threadIdx.x;
    int j = idx & 7;
    int lane = (idx >> 3) & 63;
    int ctchunk = idx >> 9;
    int ct = ctchunk & 3;
    int chunk = ctchunk >> 2;
    int k = chunk * 32 + ((lane >> 4) << 3) + j;
    int col = ct * 16 + (lane & 15);
    W1pack[idx] = f2b(W1[k * 64 + col]);
  } else {
    // foldw: 512 outputs with 256 threads, 2 iterations
    for (int t = threadIdx.x; t < 512; t += NT) {
      int k = t >> 3, h = t & 7;
      float sl = 0.f, sr = 0.f;
      for (int f = 0; f < 64; ++f) {
        float w = W2[k * 512 + h * 64 + f];
        sl += w * attl2[h * 64 + f];
        sr += w * attr2[h * 64 + f];
      }
      wl[k * 8 + h] = sl;
      wr[k * 8 + h] = sr;
    }
  }
}

// ---- layer 1 MFMA GEMM + fused attention dots ----
__global__ void __launch_bounds__(NT)
gemm1_mfma_kernel(const float* __restrict__ x, const unsigned short* __restrict__ W1pack,
                  const float* __restrict__ attl, const float* __restrict__ attr,
                  unsigned short* __restrict__ xl1b, float* __restrict__ a1, int N) {
  int w = threadIdx.x >> 6;
  int lane = threadIdx.x & 63;
  int colb = lane & 15;
  int rgrp = lane >> 4;            // 0..3
  int row0w = blockIdx.x * 64 + w * 16;
  int arow = row0w + colb;
  if (arow >= N) arow = N - 1;     // clamp; stores guarded
  const float* ap = x + (size_t)arow * 128 + (rgrp << 3);

  f32x4 acc[4];
#pragma unroll
  for (int ct = 0; ct < 4; ++ct) { acc[ct][0] = 0.f; acc[ct][1] = 0.f; acc[ct][2] = 0.f; acc[ct][3] = 0.f; }

#pragma unroll
  for (int chunk = 0; chunk < 4; ++chunk) {
    float4 v0 = *(const float4*)(ap + chunk * 32);
    float4 v1 = *(const float4*)(ap + chunk * 32 + 4);
    bf16x8 a;
    a[0] = (short)f2b(v0.x); a[1] = (short)f2b(v0.y);
    a[2] = (short)f2b(v0.z); a[3] = (short)f2b(v0.w);
    a[4] = (short)f2b(v1.x); a[5] = (short)f2b(v1.y);
    a[6] = (short)f2b(v1.z); a[7] = (short)f2b(v1.w);
    const unsigned short* bp = W1pack + ((size_t)chunk * 4 * 64 + lane) * 8;
#pragma unroll
    for (int ct = 0; ct < 4; ++ct) {
      bf16x8 b = *(const bf16x8*)(bp + (size_t)ct * 64 * 8);
      acc[ct] = __builtin_amdgcn_mfma_f32_16x16x32_bf16(a, b, acc[ct], 0, 0, 0);
    }
  }

#pragma unroll
  for (int ct = 0; ct < 4; ++ct) {
    float attlc = attl[ct * 16 + colb];
    float attrc = attr[ct * 16 + colb];
    int h = ct * 2 + (colb >> 3);
#pragma unroll
    for (int r = 0; r < 4; ++r) {
      int n = row0w + rgrp * 4 + r;
      float v = acc[ct][r];
      if (n < N) xl1b[(size_t)n * 64 + ct * 16 + colb] = f2b(v);
      float pl = v * attlc;
      float pr = v * attrc;
      pl += __shfl_xor(pl, 1, 64); pr += __shfl_xor(pr, 1, 64);
      pl += __shfl_xor(pl, 2, 64); pr += __shfl_xor(pr, 2, 64);
      pl += __shfl_xor(pl, 4, 64); pr += __shfl_xor(pr, 4, 64);
      if ((lane & 7) == 0 && n < N) {
        a1[n * 16 + h] = pl;
        a1[n * 16 + 8 + h] = pr;
      }
    }
  }
}

// ---- layer1: single-pass softmax+aggregation ----
__global__ void __launch_bounds__(NT)
node_aggr1_kernel(const int* __restrict__ rowptr, const int* __restrict__ csr_src,
                  const float* __restrict__ a1, const unsigned short* __restrict__ xl1b,
                  const float* __restrict__ b1, unsigned short* __restrict__ hrb, int N) {
  __shared__ float ps[4][64][8];
  __shared__ int ss[4][64];
  int w = threadIdx.x >> 6;
  int n = blockIdx.x * 4 + w;
  if (n >= N) return;
  int lane = threadIdx.x & 63;
  int hstage = lane & 7;
  int j8 = lane >> 3;
  int hown = lane >> 3;
  int base = rowptr[n];
  int deg = rowptr[n + 1] - base;

  float arh = a1[n * 16 + 8 + hstage];
  const unsigned short* xp = xl1b + lane;
  float acc = 0.f, dn = 0.f;

  for (int j0 = 0; j0 < deg; j0 += 64) {
    int cnt = deg - j0; if (cnt > 64) cnt = 64;
    if (lane < cnt) ss[w][lane] = csr_src[base + j0 + lane];
    asm volatile("s_waitcnt lgkmcnt(0)" ::: "memory");
    for (int jj = 0; jj < cnt; jj += 8) {
      int j = jj + j8;
      if (j < cnt) {
        int s = ss[w][j];
        float p = __expf(lrelu(a1[(unsigned)s * 16 + hstage] + arh));
        ps[w][j][hstage] = p;
      }
    }
    asm volatile("s_waitcnt lgkmcnt(0)" ::: "memory");
    int j = 0;
    for (; j + 4 <= cnt; j += 4) {
      int s0 = ss[w][j+0], s1 = ss[w][j+1], s2 = ss[w][j+2], s3 = ss[w][j+3];
      float p0 = ps[w][j+0][hown], p1 = ps[w][j+1][hown];
      float p2 = ps[w][j+2][hown], p3 = ps[w][j+3][hown];
      float v0 = b2f(xp[(unsigned)s0 * 64]), v1 = b2f(xp[(unsigned)s1 * 64]);
      float v2 = b2f(xp[(unsigned)s2 * 64]), v3 = b2f(xp[(unsigned)s3 * 64]);
      dn += (p0 + p1) + (p2 + p3);
      acc += p0 * v0 + p1 * v1 + p2 * v2 + p3 * v3;
    }
    for (; j < cnt; ++j) {
      int s = ss[w][j];
      float p = ps[w][j][hown];
      dn += p;
      acc += p * b2f(xp[(unsigned)s * 64]);
    }
  }
  acc = acc / (dn + 1e-16f);
  float hv = fmaxf(acc + b1[lane], 0.f);   // relu(out1 + b1)
  hrb[(size_t)n * 64 + lane] = f2b(hv);
}

// ---- layer-2 attention dots as a streaming kernel ----
#define A2N 256
__global__ void __launch_bounds__(NT)
a2dots_kernel(const unsigned short* __restrict__ hrb, const float* __restrict__ wl,
              const float* __restrict__ wr, float* __restrict__ a2, int N) {
  __shared__ unsigned short hs[A2N][65];
  __shared__ float wls[64 * 8], wrs[64 * 8];
  int tid = threadIdx.x;
  int n0 = blockIdx.x * A2N;
  for (int i = tid; i < 512; i += NT) { wls[i] = wl[i]; wrs[i] = wr[i]; }
  for (int i = tid; i < A2N * 8; i += NT) {
    int r = i >> 3, seg = i & 7;
    int n = n0 + r;
    uint4 v = make_uint4(0, 0, 0, 0);
    if (n < N) v = *(const uint4*)&hrb[(size_t)n * 64 + seg * 8];
    int c = seg * 8;
    hs[r][c + 0] = (unsigned short)(v.x);
    hs[r][c + 1] = (unsigned short)(v.x >> 16);
    hs[r][c + 2] = (unsigned short)(v.y);
    hs[r][c + 3] = (unsigned short)(v.y >> 16);
    hs[r][c + 4] = (unsigned short)(v.z);
    hs[r][c + 5] = (unsigned short)(v.z >> 16);
    hs[r][c + 6] = (unsigned short)(v.w);
    hs[r][c + 7] = (unsigned short)(v.w >> 16);
  }
  __syncthreads();
  float tl[8], tr[8];
#pragma unroll
  for (int h = 0; h < 8; ++h) { tl[h] = 0.f; tr[h] = 0.f; }
#pragma unroll 4
  for (int k = 0; k < 64; ++k) {
    float hv = b2f(hs[tid][k]);
    float4 l0 = *(const float4*)&wls[k * 8];
    float4 l1 = *(const float4*)&wls[k * 8 + 4];
    float4 r0 = *(const float4*)&wrs[k * 8];
    float4 r1 = *(const float4*)&wrs[k * 8 + 4];
    tl[0] += hv * l0.x; tl[1] += hv * l0.y; tl[2] += hv * l0.z; tl[3] += hv * l0.w;
    tl[4] += hv * l1.x; tl[5] += hv * l1.y; tl[6] += hv * l1.z; tl[7] += hv * l1.w;
    tr[0] += hv * r0.x; tr[1] += hv * r0.y; tr[2] += hv * r0.z; tr[3] += hv * r0.w;
    tr[4] += hv * r1.x; tr[5] += hv * r1.y; tr[6] += hv * r1.z; tr[7] += hv * r1.w;
  }
  int n = n0 + tid;
  if (n < N) {
    *(float4*)&a2[n * 16 + 0]  = make_float4(tl[0], tl[1], tl[2], tl[3]);
    *(float4*)&a2[n * 16 + 4]  = make_float4(tl[4], tl[5], tl[6], tl[7]);
    *(float4*)&a2[n * 16 + 8]  = make_float4(tr[0], tr[1], tr[2], tr[3]);
    *(float4*)&a2[n * 16 + 12] = make_float4(tr[4], tr[5], tr[6], tr[7]);
  }
}

// ---- layer2: single-pass softmax+aggregation -> normalized g (bf16) ----
__global__ void __launch_bounds__(NT)
node_aggr2_kernel(const int* __restrict__ rowptr, const int* __restrict__ csr_src,
                  const float* __restrict__ a2, const unsigned short* __restrict__ hrb,
                  unsigned short* __restrict__ gb, int N) {
  __shared__ float ps[4][64][8];
  __shared__ int ss[4][64];
  int w = threadIdx.x >> 6;
  int n = blockIdx.x * 4 + w;
  if (n >= N) return;
  int lane = threadIdx.x & 63;
  int hstage = lane & 7;
  int j8 = lane >> 3;
  int base = rowptr[n];
  int deg = rowptr[n + 1] - base;

  float arh = a2[n * 16 + 8 + hstage];
  const unsigned short* hp = hrb + lane;
  float acc[8] = {0.f, 0.f, 0.f, 0.f, 0.f, 0.f, 0.f, 0.f};
  float dn_own = 0.f;

  for (int j0 = 0; j0 < deg; j0 += 64) {
    int cnt = deg - j0; if (cnt > 64) cnt = 64;
    if (lane < cnt) ss[w][lane] = csr_src[base + j0 + lane];
    asm volatile("s_waitcnt lgkmcnt(0)" ::: "memory");
    for (int jj = 0; jj < cnt; jj += 8) {
      int j = jj + j8;
      if (j < cnt) {
        int s = ss[w][j];
        float p = __expf(lrelu(a2[(unsigned)s * 16 + hstage] + arh));
        ps[w][j][hstage] = p;
      }
    }
    asm volatile("s_waitcnt lgkmcnt(0)" ::: "memory");
    for (int j = 0; j < cnt; ++j) {
      int s = ss[w][j];
      float hv = b2f(hp[(unsigned)s * 64]);
      float4 pa = *(const float4*)&ps[w][j][0];
      float4 pb = *(const float4*)&ps[w][j][4];
      dn_own += ps[w][j][hstage];
      acc[0] += pa.x * hv; acc[1] += pa.y * hv; acc[2] += pa.z * hv; acc[3] += pa.w * hv;
      acc[4] += pb.x * hv; acc[5] += pb.y * hv; acc[6] += pb.z * hv; acc[7] += pb.w * hv;
    }
  }
#pragma unroll
  for (int h = 0; h < 8; ++h) {
    float dnh = __shfl(dn_own, h, 64);
    float v = acc[h] * (1.f / (dnh + 1e-16f));
    gb[(size_t)n * 512 + h * 64 + lane] = f2b(v);
  }
}

// ---- MFMA epilogue GEMM: out[N,64] = gb[N,512](bf16) @ Bpack + b2 ----
__global__ void __launch_bounds__(NT)
gemm3_mfma_kernel(const unsigned short* __restrict__ gb,
                  const unsigned short* __restrict__ Bpack,
                  const float* __restrict__ b2, float* __restrict__ out, int N) {
  int w = threadIdx.x >> 6;
  int lane = threadIdx.x & 63;
  int row0w = blockIdx.x * 64 + w * 16;
  int arow = row0w + (lane & 15);
  if (arow >= N) arow = N - 1;          // clamp (stores are guarded)
  const unsigned short* ap = gb + (size_t)arow * 512 + ((lane >> 4) << 3);

  f32x4 acc[4];
#pragma unroll
  for (int ct = 0; ct < 4; ++ct) {
    float bb = b2[ct * 16 + (lane & 15)];
    acc[ct][0] = bb; acc[ct][1] = bb; acc[ct][2] = bb; acc[ct][3] = bb;
  }

#pragma unroll 4
  for (int chunk = 0; chunk < 16; ++chunk) {
    bf16x8 a = *(const bf16x8*)(ap + chunk * 32);
    const unsigned short* bp = Bpack + ((size_t)chunk * 4 * 64 + lane) * 8;
#pragma unroll
    for (int ct = 0; ct < 4; ++ct) {
      bf16x8 b = *(const bf16x8*)(bp + (size_t)ct * 64 * 8);
      acc[ct] = __builtin_amdgcn_mfma_f32_16x16x32_bf16(a, b, acc[ct], 0, 0, 0);
    }
  }

  int orow0 = row0w + ((lane >> 4) << 2);
#pragma unroll
  for (int ct = 0; ct < 4; ++ct) {
    int col = ct * 16 + (lane & 15);
#pragma unroll
    for (int r = 0; r < 4; ++r) {
      int n = orow0 + r;
      if (n < N) out[(size_t)n * 64 + col] = acc[ct][r];
    }
  }
}

extern "C" void kernel_launch(void* const* d_in, const int* in_sizes, int n_in,
                              void* d_out, int out_size, void* d_ws, size_t ws_size,
                              hipStream_t stream) {
  const float* x     = (const float*)d_in[0];
  const void*  ei    = d_in[1];
  const float* W1    = (const float*)d_in[2];
  const float* attl1 = (const float*)d_in[3];
  const float* attr1 = (const float*)d_in[4];
  const float* b1    = (const float*)d_in[5];
  const float* W2    = (const float*)d_in[6];
  const float* attl2 = (const float*)d_in[7];
  const float* attr2 = (const float*)d_in[8];
  const float* b2    = (const float*)d_in[9];
  float* out = (float*)d_out;

  int N = in_sizes[0] / 128;
  int E = in_sizes[1] / 2;

  int nblk = (E + CHUNK - 1) / CHUNK;
  int nbk  = (N + (1 << BSHIFT) - 1) >> BSHIFT;
  int L    = nbk * nblk;
  int zblk = (N + NT - 1) / NT;
  int gblk = nblk > zblk ? nblk : zblk;

  char* ws = (char*)d_ws;
  size_t off = 0;
  auto alloc = [&](size_t bytes) {
    char* p = ws + off;
    off += (bytes + 255) & ~size_t(255);
    return p;
  };
  int*            edges   = (int*)alloc((size_t)2 * E * 4);
  int*            flag    = (int*)alloc(256);
  int*            deg     = (int*)alloc((size_t)N * 4);
  int*            cursor  = (int*)alloc((size_t)N * 4);
  int*            rowptr  = (int*)alloc((size_t)(N + 1) * 4);
  int*            bsum    = (int*)alloc(1024);
  int*            boff    = (int*)alloc(1024);
  int*            blkcnt  = (int*)alloc((size_t)L * 4);
  int*            basebuf = (int*)alloc((size_t)(L + 1) * 4);
  int*            bsum2   = (int*)alloc(1024);
  int*            boff2   = (int*)alloc(1024);
  long long*      binned  = (long long*)alloc((size_t)E * 8);
  int*            csr_src = (int*)alloc((size_t)E * 4);
  unsigned short* xl1b    = (unsigned short*)alloc((size_t)N * 64 * 2);
  float*          a1      = (float*)alloc((size_t)N * 16 * 4);
  unsigned short* hrb     = (unsigned short*)alloc((size_t)N * 64 * 2);
  float*          a2      = (float*)alloc((size_t)N * 16 * 4);
  float*          wl      = (float*)alloc(64 * 8 * 4);
  float*          wr      = (float*)alloc(64 * 8 * 4);
  unsigned short* Bpack   = (unsigned short*)alloc(512 * 64 * 2);
  unsigned short* W1pack  = (unsigned short*)alloc(128 * 64 * 2);
  unsigned short* gb      = (unsigned short*)alloc((size_t)N * 512 * 2);
  (void)ws_size;

  const int* srcp = edges;
  const int* dstp = edges + E;
  int SB  = (N + 1 + NT - 1) / NT;    // <= 256
  int SBL = (L + 1 + NT - 1) / NT;    // <= 256

  detect_kernel<<<1, NT, 0, stream>>>((const int*)ei, flag, 2 * E);

  // phase A: fused convert + bucket histogram + deg/cursor zero
  cvtbin_kernel<<<gblk, NT, 0, stream>>>(ei, flag, edges, blkcnt, deg, cursor, E, N, nblk, nbk);
  scan1_kernel<<<SBL, NT, 0, stream>>>(blkcnt, bsum2, L);
  scan2_kernel<<<1, NT, 0, stream>>>(bsum2, boff2, SBL);
  scan3_kernel<<<SBL, NT, 0, stream>>>(blkcnt, boff2, basebuf, L);
  binwrite_kernel<<<nblk, NT, 0, stream>>>(srcp, dstp, basebuf, binned, E, nblk, nbk);

  // degree histogram (bucket-local) + rowptr
  deghist_kernel<<<(E + NT - 1) / NT, NT, 0, stream>>>(binned, deg, E);
  scan1_kernel<<<SB, NT, 0, stream>>>(deg, bsum, N);
  scan2_kernel<<<1, NT, 0, stream>>>(bsum, boff, SB);
  scan3_kernel<<<SB, NT, 0, stream>>>(deg, boff, rowptr, N);

  // phase B: locality-friendly CSR scatter
  scatter2_kernel<<<(E + NT - 1) / NT, NT, 0, stream>>>(binned, rowptr, cursor, csr_src, E);

  // dense precomputation (single fused pack kernel + MFMA gemm1)
  foldall_kernel<<<161, NT, 0, stream>>>(W1, W2, attl2, attr2, W1pack, Bpack, wl, wr);
  gemm1_mfma_kernel<<<(N + 63) / 64, NT, 0, stream>>>(x, W1pack, attl1, attr1, xl1b, a1, N);

  // layer 1 aggregation (+ fused relu/bias)
  node_aggr1_kernel<<<(N + 3) / 4, NT, 0, stream>>>(rowptr, csr_src, a1, xl1b, b1, hrb, N);

  // layer-2 attention dots (streaming)
  a2dots_kernel<<<(N + A2N - 1) / A2N, NT, 0, stream>>>(hrb, wl, wr, a2, N);

  // layer 2 aggregation -> g (bf16), then MFMA epilogue
  node_aggr2_kernel<<<(N + 3) / 4, NT, 0, stream>>>(rowptr, csr_src, a2, hrb, gb, N);
  gemm3_mfma_kernel<<<(N + 63) / 64, NT, 0, stream>>>(gb, Bpack, b2, out, N);
}